// Round 1
// 1171.397 us; speedup vs baseline: 1.1187x; 1.1187x over previous
//
#include <hip/hip_runtime.h>
#include <hip/hip_bf16.h>
#include <cstdint>
#include <cstddef>

typedef unsigned short u16;
typedef __attribute__((ext_vector_type(8))) short short8;
typedef __attribute__((ext_vector_type(4))) float f4;

// ---------- helpers ----------

__device__ __forceinline__ u16 f2bf(float x) {
    union { float f; uint32_t u; } v; v.f = x;
    uint32_t r = v.u + 0x7fffu + ((v.u >> 16) & 1u);   // RNE
    return (u16)(r >> 16);
}

__device__ __forceinline__ void async16(const u16* g, u16* l) {
    __builtin_amdgcn_global_load_lds((__attribute__((address_space(1))) void*)(g),
                                     (__attribute__((address_space(3))) void*)(l),
                                     16, 0, 0);
}

// ---------- bf16 MFMA GEMM, double-buffered, 1 barrier/kt ----------
// A: fp32 row-major (lda=K), converted to bf16 in registers during staging.
//    LDS layout: per row 4 chunks of 8 bf16, chunk XOR-swizzled:
//    pos(row,c) = row*4 + (c ^ ((row>>1)&3))  -> conflict-free write AND read.
// Bt: pre-tiled chunk-major weights [KT][4][BN][8] bf16 (zero-padded K).
//    Staged linearly by global_load_lds; read granule = l16 mod 8 (clean).
// SCORES: fuse per-node attention logits (es/ed) into the epilogue.

template<int BM, int BN, int WM, int WN, bool SCORES>
__global__ __launch_bounds__((BM/WM)*(BN/WN)*64)
void gemm_xw(const float* __restrict__ A, const u16* __restrict__ Bt,
             float* __restrict__ C, int M, int K, int KT, int ktPer,
             const float* __restrict__ asrc, const float* __restrict__ adst,
             float* __restrict__ es, float* __restrict__ ed, int Hs)
{
    constexpr int WAVES   = (BM/WM)*(BN/WN);
    constexpr int THREADS = WAVES*64;
    constexpr int RF = WM/16, CF = WN/16;
    constexpr int BCH = (BN*32)/(8*THREADS);     // 16B chunks of B per thread
    static_assert((BM*32)/THREADS == 8, "A staging assumes 8 floats per thread");

    __shared__ __align__(16) u16 As[2][BM*32];
    __shared__ __align__(16) u16 Bs[2][BN*32];

    const int tid  = threadIdx.x;
    const int wid  = tid >> 6, lane = tid & 63;
    const int quad = lane >> 4, l16 = lane & 15;
    constexpr int WCOLS = BN/WN;
    const int wm = (wid / WCOLS) * WM;
    const int wn = (wid % WCOLS) * WN;
    const long m0 = (long)blockIdx.x * BM;

    const int ktA = blockIdx.y * ktPer;
    const int ktB = min(ktA + ktPer, KT);
    float* Cp = C + (size_t)blockIdx.y * (size_t)M * BN;

    // A staging: thread -> (row = tid>>2, chunk = tid&3), 8 consecutive floats
    const int arow = tid >> 2;
    const int achk = tid & 3;
    const int akk  = achk * 8;
    const bool aok = (m0 + arow) < M;
    const float* aptr = A + (size_t)(m0 + arow) * K + akk;
    const int awpos = arow*4 + (achk ^ ((arow >> 1) & 3));   // swizzled 16B slot

    // LDS read offsets (u16 units). Note: +16-row steps don't change the XOR term.
    const int aoff = (wm + l16)*32 + (quad ^ (((wm + l16) >> 1) & 3))*8;
    const int boff = quad*(BN*8) + (wn + l16)*8;

    f4 acc[RF][CF];
    #pragma unroll
    for (int r = 0; r < RF; ++r)
        #pragma unroll
        for (int c = 0; c < CF; ++c)
            #pragma unroll
            for (int g = 0; g < 4; ++g) acc[r][c][g] = 0.f;

    f4 v0, v1;

    auto stageB = [&](int kt, int buf) {
        #pragma unroll
        for (int i = 0; i < BCH; ++i) {
            int c16 = i*THREADS + tid;
            async16(Bt + (size_t)kt*(BN*32) + (size_t)c16*8, (u16*)Bs[buf] + c16*8);
        }
    };
    auto loadA = [&](int kt) {
        #pragma unroll
        for (int g = 0; g < 4; ++g) { v0[g] = 0.f; v1[g] = 0.f; }
        const int gk = kt*32 + akk;
        if (aok && gk < K) {
            const float* p = aptr + (size_t)kt*32;
            v0 = *(const f4*)p;
            v1 = *(const f4*)(p + 4);
        }
    };
    auto writeA = [&](int buf) {
        short8 w;
        #pragma unroll
        for (int g = 0; g < 4; ++g) {
            w[g]   = (short)f2bf(v0[g]);
            w[4+g] = (short)f2bf(v1[g]);
        }
        *(short8*)((u16*)As[buf] + awpos*8) = w;
    };

    // prologue: fill buffer 0
    stageB(ktA, 0);
    loadA(ktA);
    writeA(0);
    __syncthreads();

    for (int kt = ktA; kt < ktB; ++kt) {
        const int cur = (kt - ktA) & 1;
        const bool pf = (kt + 1) < ktB;
        if (pf) {                       // issue next-tile loads right after barrier
            stageB(kt + 1, cur ^ 1);    // async -> other buffer (free since barrier)
            loadA(kt + 1);              // global -> regs, consumed after MFMA
        }
        short8 af[RF], bfr[CF];
        #pragma unroll
        for (int r = 0; r < RF; ++r) af[r]  = *(const short8*)((u16*)As[cur] + aoff + r*512);
        #pragma unroll
        for (int c = 0; c < CF; ++c) bfr[c] = *(const short8*)((u16*)Bs[cur] + boff + c*128);
        #pragma unroll
        for (int r = 0; r < RF; ++r)
            #pragma unroll
            for (int c = 0; c < CF; ++c)
                acc[r][c] = __builtin_amdgcn_mfma_f32_16x16x32_bf16(af[r], bfr[c], acc[r][c], 0, 0, 0);
        if (pf) writeA(cur ^ 1);        // vmcnt wait for loadA lands here (post-MFMA)
        __syncthreads();                // buf cur^1 complete; buf cur free
    }

    // epilogue: D[m=quad*4+g][n=l16]
    #pragma unroll
    for (int r = 0; r < RF; ++r) {
        const long rb = m0 + wm + r*16 + quad*4;
        #pragma unroll
        for (int c = 0; c < CF; ++c) {
            const int col = wn + c*16 + l16;
            #pragma unroll
            for (int g = 0; g < 4; ++g) {
                long row = rb + g;
                if (row < M) Cp[row*(long)BN + col] = acc[r][c][g];
            }
        }
    }

    if constexpr (SCORES) {
        // Each wave owns one head's 64 cols (WN==64) for its rows: full dot
        // products live in this wave's accumulator. 16-lane shfl reduce.
        const int head = wn >> 6;
        float av[CF], dv[CF];
        #pragma unroll
        for (int c = 0; c < CF; ++c) {
            av[c] = asrc[head*64 + c*16 + l16];
            dv[c] = adst[head*64 + c*16 + l16];
        }
        #pragma unroll
        for (int r = 0; r < RF; ++r) {
            #pragma unroll
            for (int g = 0; g < 4; ++g) {
                float s = 0.f, d = 0.f;
                #pragma unroll
                for (int c = 0; c < CF; ++c) {
                    s += acc[r][c][g] * av[c];
                    d += acc[r][c][g] * dv[c];
                }
                #pragma unroll
                for (int off = 1; off < 16; off <<= 1) {
                    s += __shfl_xor(s, off);
                    d += __shfl_xor(d, off);
                }
                long row = m0 + wm + r*16 + quad*4 + g;
                if (l16 == 0 && row < M) {
                    es[row*Hs + head] = s;
                    ed[row*Hs + head] = d;
                }
            }
        }
    }
}

// ---------- split-K reduce + attention scores (layer-1 epilogue) ----------
__global__ void k_reduce_scores(const float* __restrict__ parts, size_t partStride, int S,
                                const float* __restrict__ asrc, const float* __restrict__ adst,
                                float* __restrict__ h, float* __restrict__ es,
                                float* __restrict__ ed, int N)
{
    int wave = threadIdx.x >> 6, lane = threadIdx.x & 63;
    int node = blockIdx.x*4 + wave;
    if (node >= N) return;
    size_t base = (size_t)node*256 + lane*4;
    f4 v;
    #pragma unroll
    for (int g = 0; g < 4; ++g) v[g] = 0.f;
    for (int s = 0; s < S; ++s) {
        f4 p = *(const f4*)(parts + s*partStride + base);
        #pragma unroll
        for (int g = 0; g < 4; ++g) v[g] += p[g];
    }
    *(f4*)(h + base) = v;

    int hh = lane >> 4;                 // head
    int c0 = (lane & 15) * 4;           // col within head
    float s = 0.f, d = 0.f;
    #pragma unroll
    for (int g = 0; g < 4; ++g) {
        s += v[g] * asrc[hh*64 + c0 + g];
        d += v[g] * adst[hh*64 + c0 + g];
    }
    #pragma unroll
    for (int off = 1; off < 16; off <<= 1) {
        s += __shfl_xor(s, off);
        d += __shfl_xor(d, off);
    }
    if ((lane & 15) == 0) { es[node*4 + hh] = s; ed[node*4 + hh] = d; }
}

// ---------- weight prep: W[K x Nn] fp32 -> Bt[KT][4][Nn][8] bf16 (chunk-major) ----------
__global__ void k_prep_w(const float* __restrict__ W, u16* __restrict__ out,
                         int K, int Nn, int total)
{
    int idx = blockIdx.x*256 + threadIdx.x;
    if (idx >= total) return;
    int k7 = idx & 7;
    int t  = idx >> 3;
    int nn = t % Nn;
    int u  = t / Nn;
    int cc = u & 3;
    int kt = u >> 2;
    int k = kt*32 + cc*8 + k7;
    float v = (k < K) ? W[(size_t)k*Nn + nn] : 0.f;
    out[idx] = f2bf(v);
}

// ---------- CSR build ----------
__global__ void k_hist(const int* __restrict__ ei, int E, int N, int* counts)
{
    int i = blockIdx.x*256 + threadIdx.x;
    if (i >= E + N) return;
    int d = (i < E) ? ei[E + i] : (i - E);   // self-loop tail
    atomicAdd(&counts[d], 1);
}

__global__ void k_scan1(const int* __restrict__ counts, int* offs, int* partials, int N)
{
    __shared__ int s[256];
    int i = blockIdx.x*256 + threadIdx.x;
    int v = (i < N) ? counts[i] : 0;
    s[threadIdx.x] = v;
    __syncthreads();
    #pragma unroll
    for (int off = 1; off < 256; off <<= 1) {
        int t = (threadIdx.x >= off) ? s[threadIdx.x - off] : 0;
        __syncthreads();
        s[threadIdx.x] += t;
        __syncthreads();
    }
    if (i < N) offs[i + 1] = s[threadIdx.x];
    if (threadIdx.x == 255) partials[blockIdx.x] = s[255];
    if (i == 0) offs[0] = 0;
}

__global__ void k_scan2(int* partials, int NB)
{
    __shared__ int s[256];
    int v = (threadIdx.x < NB) ? partials[threadIdx.x] : 0;
    s[threadIdx.x] = v;
    __syncthreads();
    for (int off = 1; off < 256; off <<= 1) {
        int t = (threadIdx.x >= off) ? s[threadIdx.x - off] : 0;
        __syncthreads();
        s[threadIdx.x] += t;
        __syncthreads();
    }
    if (threadIdx.x < NB) partials[threadIdx.x] = s[threadIdx.x] - v;  // exclusive
}

__global__ void k_scan3(int* offs, const int* __restrict__ partials, int N)
{
    int i = blockIdx.x*256 + threadIdx.x;
    if (i < N) offs[i + 1] += partials[blockIdx.x];
}

__global__ void k_copy(const int* __restrict__ a, int* __restrict__ b, int n)
{
    int i = blockIdx.x*256 + threadIdx.x;
    if (i < n) b[i] = a[i];
}

__global__ void k_scatter(const int* __restrict__ ei, int E, int N,
                          int* cursor, int* __restrict__ ssrc)
{
    int i = blockIdx.x*256 + threadIdx.x;
    if (i >= E + N) return;
    int s, d;
    if (i < E) { s = ei[i]; d = ei[E + i]; } else { s = i - E; d = s; }
    int pos = atomicAdd(&cursor[d], 1);
    ssrc[pos] = s;
}

// ---------- edge-parallel online-softmax aggregation, H=4 ----------
// wave per node. Lane layout: hh = lane>>4 (head), e16 = lane&15 (edge slot).
// Chunk of 16 edges: all es gathers in parallel, shfl max/sum per 16-lane
// group, branchless rescale, then float4 h-row gathers with 4-deep unroll
// (independent loads -> latency hidden by ILP). Each lane accumulates
// features [lane*4, lane*4+4) of the 256-wide row.
__global__ void k_agg4(const float* __restrict__ h, const int* __restrict__ offs,
                       const int* __restrict__ ssrc, const float* __restrict__ es,
                       const float* __restrict__ ed, const float* __restrict__ bias,
                       float* __restrict__ out, int N)
{
    const int wid = threadIdx.x >> 6, lane = threadIdx.x & 63;
    const int n = blockIdx.x*4 + wid;
    if (n >= N) return;
    const int s0 = offs[n], s1 = offs[n + 1];
    const int hh   = lane >> 4;
    const int e16  = lane & 15;
    const int psrc = lane & 48;          // base lane of this head's group
    const float edv = ed[n*4 + hh];
    float m = -1e30f, l = 0.f;
    f4 acc;
    #pragma unroll
    for (int g = 0; g < 4; ++g) acc[g] = 0.f;

    for (int c0 = s0; c0 < s1; c0 += 16) {
        const int jj = c0 + e16;
        const bool valid = jj < s1;
        int sidx = valid ? ssrc[jj] : 0;
        float e = -1e30f;
        if (valid) {
            e = es[sidx*4 + hh] + edv;
            e = (e > 0.f) ? e : 0.2f*e;
        }
        float cm = e;
        #pragma unroll
        for (int off = 1; off < 16; off <<= 1) cm = fmaxf(cm, __shfl_xor(cm, off));
        const float nm = fmaxf(m, cm);            // branchless rescale (per-head
        const float sc = __expf(m - nm);          // max differs across quads)
        l *= sc;
        #pragma unroll
        for (int g = 0; g < 4; ++g) acc[g] *= sc;
        m = nm;
        float p = valid ? __expf(e - m) : 0.f;
        float ps = p;
        #pragma unroll
        for (int off = 1; off < 16; off <<= 1) ps += __shfl_xor(ps, off);
        l += ps;

        const int cnt = min(s1 - c0, 16);
        int j = 0;
        for (; j + 4 <= cnt; j += 4) {
            int sa = __shfl(sidx, j),     sb = __shfl(sidx, j + 1);
            int sc2 = __shfl(sidx, j + 2), sd = __shfl(sidx, j + 3);
            float pa = __shfl(p, psrc + j),     pb = __shfl(p, psrc + j + 1);
            float pc = __shfl(p, psrc + j + 2), pd = __shfl(p, psrc + j + 3);
            f4 ha = *(const f4*)(h + (size_t)sa*256  + lane*4);
            f4 hb = *(const f4*)(h + (size_t)sb*256  + lane*4);
            f4 hc = *(const f4*)(h + (size_t)sc2*256 + lane*4);
            f4 hd = *(const f4*)(h + (size_t)sd*256  + lane*4);
            #pragma unroll
            for (int g = 0; g < 4; ++g)
                acc[g] += pa*ha[g] + pb*hb[g] + pc*hc[g] + pd*hd[g];
        }
        for (; j < cnt; ++j) {
            int s_ = __shfl(sidx, j);
            float p_ = __shfl(p, psrc + j);
            f4 hv = *(const f4*)(h + (size_t)s_*256 + lane*4);
            #pragma unroll
            for (int g = 0; g < 4; ++g) acc[g] += p_*hv[g];
        }
    }
    const float inv = 1.f / l;
    f4 b4 = *(const f4*)(bias + lane*4);
    f4 o;
    #pragma unroll
    for (int g = 0; g < 4; ++g) {
        float v = acc[g]*inv + b4[g];
        o[g] = (v > 0.f) ? v : (__expf(v) - 1.f);
    }
    *(f4*)(out + (size_t)n*256 + lane*4) = o;
}

// ---------- layer-3 aggregation (H=1) + fused classifier ----------
// wave per node, lane = feature (64). Chunks of 64 edges, edge-parallel
// max/sum, unrolled independent gathers. Epilogue computes the 3 logits
// via shfl reduction and writes d_out directly.
__global__ void k_agg1_cls(const float* __restrict__ h, const int* __restrict__ offs,
                           const int* __restrict__ ssrc, const float* __restrict__ es,
                           const float* __restrict__ ed, const float* __restrict__ bias,
                           const float* __restrict__ Wc, const float* __restrict__ bc,
                           float* __restrict__ out, int N)
{
    const int wid = threadIdx.x >> 6, lane = threadIdx.x & 63;
    const int n = blockIdx.x*4 + wid;
    if (n >= N) return;
    const int s0 = offs[n], s1 = offs[n + 1];
    const float edv = ed[n];
    float m = -1e30f, l = 0.f, acc = 0.f;

    for (int c0 = s0; c0 < s1; c0 += 64) {
        const int jj = c0 + lane;
        const bool valid = jj < s1;
        int sidx = valid ? ssrc[jj] : 0;
        float e = -1e30f;
        if (valid) {
            e = es[sidx] + edv;
            e = (e > 0.f) ? e : 0.2f*e;
        }
        float cm = e;
        #pragma unroll
        for (int off = 32; off > 0; off >>= 1) cm = fmaxf(cm, __shfl_xor(cm, off));
        if (cm > m) {                   // wave-uniform
            float sc = __expf(m - cm);
            l *= sc; acc *= sc; m = cm;
        }
        float p = valid ? __expf(e - m) : 0.f;
        float ps = p;
        #pragma unroll
        for (int off = 32; off > 0; off >>= 1) ps += __shfl_xor(ps, off);
        l += ps;

        const int cnt = min(s1 - c0, 64);
        int j = 0;
        for (; j + 4 <= cnt; j += 4) {
            int sa = __shfl(sidx, j),     sb = __shfl(sidx, j + 1);
            int sc2 = __shfl(sidx, j + 2), sd = __shfl(sidx, j + 3);
            float pa = __shfl(p, j),     pb = __shfl(p, j + 1);
            float pc = __shfl(p, j + 2), pd = __shfl(p, j + 3);
            acc += pa*h[(size_t)sa*64  + lane] + pb*h[(size_t)sb*64  + lane]
                 + pc*h[(size_t)sc2*64 + lane] + pd*h[(size_t)sd*64  + lane];
        }
        for (; j < cnt; ++j)
            acc += __shfl(p, j) * h[(size_t)__shfl(sidx, j)*64 + lane];
    }
    float v = acc / l + bias[lane];
    v = (v > 0.f) ? v : (__expf(v) - 1.f);

    // classifier: out[n][c] = sum_lane v * Wc[lane][c] + bc[c]
    float a0 = v*Wc[lane*3 + 0], a1 = v*Wc[lane*3 + 1], a2 = v*Wc[lane*3 + 2];
    #pragma unroll
    for (int off = 32; off > 0; off >>= 1) {
        a0 += __shfl_xor(a0, off);
        a1 += __shfl_xor(a1, off);
        a2 += __shfl_xor(a2, off);
    }
    if (lane == 0) {
        out[n*3 + 0] = a0 + bc[0];
        out[n*3 + 1] = a1 + bc[1];
        out[n*3 + 2] = a2 + bc[2];
    }
}

// ---------- launcher ----------
extern "C" void kernel_launch(void* const* d_in, const int* in_sizes, int n_in,
                              void* d_out, int out_size, void* d_ws, size_t ws_size,
                              hipStream_t stream)
{
    const float* x   = (const float*)d_in[0];
    const float* W1  = (const float*)d_in[1];
    const float* a1s = (const float*)d_in[2];
    const float* a1d = (const float*)d_in[3];
    const float* b1  = (const float*)d_in[4];
    const float* W2  = (const float*)d_in[5];
    const float* a2s = (const float*)d_in[6];
    const float* a2d = (const float*)d_in[7];
    const float* b2  = (const float*)d_in[8];
    const float* W3  = (const float*)d_in[9];
    const float* a3s = (const float*)d_in[10];
    const float* a3d = (const float*)d_in[11];
    const float* b3  = (const float*)d_in[12];
    const float* Wc  = (const float*)d_in[13];
    const float* bc  = (const float*)d_in[14];
    const int*   ei  = (const int*)d_in[15];
    float* out = (float*)d_out;

    const int DIN = in_sizes[1] / 256;    // 5000
    const int N   = in_sizes[0] / DIN;    // 30000
    const int E   = in_sizes[15] / 2;     // 480000
    const int KT1 = (DIN + 31) / 32;      // 157
    const int ET  = E + N;
    const int SPLITS = 4;
    const int KTP = (KT1 + SPLITS - 1) / SPLITS;   // 40

    char* ws = (char*)d_ws;
    size_t off = 0;
    auto alloc = [&](size_t bytes) -> void* {
        void* p = ws + off;
        off += (bytes + 255) & ~(size_t)255;
        return p;
    };

    float* bufA   = (float*)alloc((size_t)N*256*4);
    float* bufB   = (float*)alloc((size_t)N*256*4);
    float* bufP   = (float*)alloc((size_t)SPLITS*N*256*4);  // split-K partials
    u16*  Wt1     = (u16*)alloc((size_t)KT1*256*32*2);
    u16*  Wt2     = (u16*)alloc((size_t)8*256*32*2);
    u16*  Wt3     = (u16*)alloc((size_t)8*64*32*2);
    float* es     = (float*)alloc((size_t)N*4*4);
    float* ed     = (float*)alloc((size_t)N*4*4);
    int* counts   = (int*)alloc((size_t)N*4);
    int* offs     = (int*)alloc((size_t)(N+1)*4);
    int* cursor   = (int*)alloc((size_t)N*4);
    int* partials = (int*)alloc(1024);
    int* ssrc     = (int*)alloc((size_t)ET*4);

    const int NB = (N + 255)/256;
    const int GM = (N + 63)/64;

    // CSR over (edges + self-loops); graph identical across the 3 layers
    hipMemsetAsync(counts, 0, (size_t)N*4, stream);
    k_hist   <<<(ET+255)/256, 256, 0, stream>>>(ei, E, N, counts);
    k_scan1  <<<NB, 256, 0, stream>>>(counts, offs, partials, N);
    k_scan2  <<<1, 256, 0, stream>>>(partials, NB);
    k_scan3  <<<NB, 256, 0, stream>>>(offs, partials, N);
    k_copy   <<<NB, 256, 0, stream>>>(offs, cursor, N);
    k_scatter<<<(ET+255)/256, 256, 0, stream>>>(ei, E, N, cursor, ssrc);

    // weights -> bf16 chunk-major tiles
    k_prep_w<<<(KT1*256*32+255)/256, 256, 0, stream>>>(W1, Wt1, DIN, 256, KT1*256*32);
    k_prep_w<<<(8*256*32+255)/256, 256, 0, stream>>>(W2, Wt2, 256, 256, 8*256*32);
    k_prep_w<<<(8*64*32+255)/256, 256, 0, stream>>>(W3, Wt3, 256, 64, 8*64*32);

    // layer 1: split-K GEMM -> fused reduce+scores -> edge-parallel agg
    gemm_xw<64,256,64,64,false><<<dim3(GM, SPLITS), 256, 0, stream>>>(
        x, Wt1, bufP, N, DIN, KT1, KTP, nullptr, nullptr, nullptr, nullptr, 0);
    k_reduce_scores<<<(N+3)/4, 256, 0, stream>>>(bufP, (size_t)N*256, SPLITS, a1s, a1d,
                                                 bufA, es, ed, N);
    k_agg4  <<<(N+3)/4, 256, 0, stream>>>(bufA, offs, ssrc, es, ed, b1, bufB, N);
    // layer 2 (scores fused into GEMM epilogue)
    gemm_xw<64,256,64,64,true><<<dim3(GM, 1), 256, 0, stream>>>(
        bufB, Wt2, bufA, N, 256, 8, 8, a2s, a2d, es, ed, 4);
    k_agg4  <<<(N+3)/4, 256, 0, stream>>>(bufA, offs, ssrc, es, ed, b2, bufB, N);
    // layer 3 (1 head; scores fused; agg fuses classifier and writes d_out)
    gemm_xw<64,64,16,64,true><<<dim3(GM, 1), 256, 0, stream>>>(
        bufB, Wt3, bufA, N, 256, 8, 8, a3s, a3d, es, ed, 1);
    k_agg1_cls<<<(N+3)/4, 256, 0, stream>>>(bufA, offs, ssrc, es, ed, b3, Wc, bc, out, N);
}